// Round 20
// baseline (166.819 us; speedup 1.0000x reference)
//
#include <hip/hip_runtime.h>
#include <hip/hip_bf16.h>
#include <math.h>

#define BB 8
#define LQ 4096
#define LK 4096
#define DD 64
#define UU 45    // top-k rows (min(5*ceil(log1p(4096)), 4096) = 45)
#define CCAP 256 // candidate capacity
#define CUMTHR 96
#define ECH 32   // exact-phase key chunks (128 keys each)
#define PCH 32   // pv/score chunks (128 keys each)
#define MCG 4    // mfmaM column groups (1024 sampled cols each)
#define GCH 32   // gather chunks (128 rows each)

typedef __bf16 bf16x8 __attribute__((ext_vector_type(8)));
typedef unsigned short ushort8 __attribute__((ext_vector_type(8)));
typedef float f32x4 __attribute__((ext_vector_type(4)));

__device__ inline unsigned short f2bf(float x) {   // RNE float->bf16 bits
    unsigned u = __builtin_bit_cast(unsigned, x);
    return (unsigned short)((u + 0x7FFF + ((u >> 16) & 1)) >> 16);
}

__device__ inline void gl_lds16(const void* g, void* l) {
    __builtin_amdgcn_global_load_lds(
        (const __attribute__((address_space(1))) unsigned int*)g,
        (__attribute__((address_space(3))) unsigned int*)l, 16, 0, 0);
}

// ---------------- K0: gather+convert sampled K rows, fused f64 partial sums
// 128 rows per chunk, 512 threads (8 waves) -> 2 gathered loads per thread.
__global__ __launch_bounds__(512) void k_gatherK(const float* __restrict__ K,
                                                 const int* __restrict__ idx,
                                                 int Upart,
                                                 unsigned short* __restrict__ Kg,
                                                 double* __restrict__ part) {
    int b = blockIdx.y;
    int chunk = blockIdx.x;
    int u0 = chunk * 128;
    int t = threadIdx.x;
    int pt = t & 7;            // d-part (8 floats each)

    double acc[8] = {0,0,0,0,0,0,0,0};
    #pragma unroll
    for (int i = 0; i < 2; ++i) {
        int lin = i * 512 + t;             // part stays == pt as i varies
        int u = u0 + (lin >> 3);
        if (u < Upart) {
            int kr = idx[u];
            const float* src = &K[((size_t)b * LK + kr) * DD + pt * 8];
            float4 v0 = *(const float4*)src;
            float4 v1 = *(const float4*)(src + 4);
            ushort8 pk;
            pk[0]=f2bf(v0.x); pk[1]=f2bf(v0.y); pk[2]=f2bf(v0.z); pk[3]=f2bf(v0.w);
            pk[4]=f2bf(v1.x); pk[5]=f2bf(v1.y); pk[6]=f2bf(v1.z); pk[7]=f2bf(v1.w);
            *(ushort8*)&Kg[((size_t)b * 4096 + u) * 64 + pt * 8] = pk;
            acc[0] += (double)v0.x; acc[1] += (double)v0.y;
            acc[2] += (double)v0.z; acc[3] += (double)v0.w;
            acc[4] += (double)v1.x; acc[5] += (double)v1.y;
            acc[6] += (double)v1.z; acc[7] += (double)v1.w;
        }
    }
    __shared__ double sred[64][64];   // 32 KB
    int rg = t >> 3;           // 0..63 row-group
    #pragma unroll
    for (int j = 0; j < 8; ++j) sred[rg][pt * 8 + j] = acc[j];
    __syncthreads();
    if (t < 64) {
        double s = 0.0;
        #pragma unroll
        for (int r = 0; r < 64; ++r) s += sred[r][t];
        part[((size_t)(b * GCH + chunk)) * 64 + t] = s;
    }
}

// ---------------- K2: approx row-max of q@Ks^T via bf16 MFMA ---------------
// Block: 256 Q-rows x 1024 sampled cols (4 iterations of 2x128-col tiles).
// Qs (32KB, transient) overlays the two Ks buffers; 2 tiles per barrier pair
// -> half the drains of the 1-tile loop. 32KB/block, 4 blocks/CU.
__global__ __launch_bounds__(256) void k_mfmaM(const float* __restrict__ Q,
                                               const unsigned short* __restrict__ Kg,
                                               float* __restrict__ maxpart) {
    int bx = blockIdx.x, cg = blockIdx.y, b = blockIdx.z;
    int t = threadIdx.x;
    int lane = t & 63, w = t >> 6;
    int row0 = bx * 256;

    __shared__ unsigned short smem[16384];   // 32 KB: Qs then Ks[2]

    // stage Q tile (reg path, f2bf, swizzled) — once per block
    for (int i = 0; i < 8; ++i) {
        int u = i * 256 + t;
        int r = u >> 3, s = u & 7;
        int c = s ^ (r & 7);
        const float* src = &Q[((size_t)b * LQ + row0 + r) * DD + c * 8];
        float4 v0 = *(const float4*)src;
        float4 v1 = *(const float4*)(src + 4);
        ushort8 pk;
        pk[0]=f2bf(v0.x); pk[1]=f2bf(v0.y); pk[2]=f2bf(v0.z); pk[3]=f2bf(v0.w);
        pk[4]=f2bf(v1.x); pk[5]=f2bf(v1.y); pk[6]=f2bf(v1.z); pk[7]=f2bf(v1.w);
        *(ushort8*)&smem[r * 64 + s * 8] = pk;
    }
    __syncthreads();   // Q staged

    // hoist A fragments to registers; Qs LDS is dead afterwards
    bf16x8 afr[4][2];
    #pragma unroll
    for (int rf = 0; rf < 4; ++rf)
        #pragma unroll
        for (int kh = 0; kh < 2; ++kh) {
            int r = w * 64 + rf * 16 + (lane & 15);
            int slot = (kh * 4 + (lane >> 4)) ^ (r & 7);
            afr[rf][kh] = __builtin_bit_cast(bf16x8, *(const ushort8*)&smem[r * 64 + slot * 8]);
        }
    __syncthreads();   // all afr reads done -> smem reusable as Ks[2]

    int krl = lane >> 3;                      // key within 8-key segment
    int kc8 = (lane & 7) ^ (krl & 7);         // inverse-swizzled global chunk
    const unsigned short* kgb = Kg + ((size_t)b * 4096 + cg * 1024) * 64;

    #define STAGE_K(buf, tile)                                                  \
        {                                                                       \
            _Pragma("unroll")                                                   \
            for (int i_ = 0; i_ < 4; ++i_) {                                    \
                int seg_ = w * 4 + i_;                                          \
                const unsigned short* g_ =                                      \
                    kgb + ((size_t)((tile) * 128 + seg_ * 8 + krl)) * 64 + kc8 * 8; \
                gl_lds16(g_, &smem[(buf) * 8192 + seg_ * 512]);                 \
            }                                                                   \
        }

    #define COMPUTE_TILE(buf)                                                   \
        {                                                                       \
            _Pragma("unroll")                                                   \
            for (int cf = 0; cf < 8; ++cf) {                                    \
                f32x4 acc[4];                                                   \
                _Pragma("unroll")                                               \
                for (int rf = 0; rf < 4; ++rf) acc[rf] = (f32x4){0.f,0.f,0.f,0.f}; \
                _Pragma("unroll")                                               \
                for (int kh = 0; kh < 2; ++kh) {                                \
                    int ccol = cf * 16 + (lane & 15);                           \
                    int slot = (kh * 4 + (lane >> 4)) ^ (ccol & 7);             \
                    bf16x8 bfr = __builtin_bit_cast(bf16x8,                     \
                        *(const ushort8*)&smem[(buf) * 8192 + ccol * 64 + slot * 8]); \
                    _Pragma("unroll")                                           \
                    for (int rf = 0; rf < 4; ++rf)                              \
                        acc[rf] = __builtin_amdgcn_mfma_f32_16x16x32_bf16(afr[rf][kh], bfr, acc[rf], 0, 0, 0); \
                }                                                               \
                _Pragma("unroll")                                               \
                for (int rf = 0; rf < 4; ++rf)                                  \
                    _Pragma("unroll")                                           \
                    for (int g = 0; g < 4; ++g)                                 \
                        rowmax[rf][g] = fmaxf(rowmax[rf][g], acc[rf][g]);       \
            }                                                                   \
        }

    STAGE_K(0, 0)
    STAGE_K(1, 1)
    __syncthreads();   // both initial tiles drained

    float rowmax[4][4];
    #pragma unroll
    for (int rf = 0; rf < 4; ++rf)
        #pragma unroll
        for (int g = 0; g < 4; ++g) rowmax[rf][g] = -INFINITY;

    for (int it = 0; it < 4; ++it) {
        COMPUTE_TILE(0)
        COMPUTE_TILE(1)
        if (it < 3) {
            __syncthreads();               // all reads of both buffers done
            STAGE_K(0, 2 * it + 2)
            STAGE_K(1, 2 * it + 3)
            __syncthreads();               // drain both prefetches
        }
    }

    #pragma unroll
    for (int rf = 0; rf < 4; ++rf)
        #pragma unroll
        for (int g = 0; g < 4; ++g) {
            float m = rowmax[rf][g];
            m = fmaxf(m, __shfl_xor(m, 1));
            m = fmaxf(m, __shfl_xor(m, 2));
            m = fmaxf(m, __shfl_xor(m, 4));
            m = fmaxf(m, __shfl_xor(m, 8));
            if ((lane & 15) == 0) {
                int row = row0 + w * 64 + rf * 16 + (lane >> 4) * 4 + g;
                maxpart[((size_t)(b * MCG + cg)) * LQ + row] = m;
            }
        }
}

// ---------------- K3: fused sumK-reduce + mt + Map -------------------------
__global__ __launch_bounds__(256) void k_meanmerge(const float* __restrict__ Q,
                                                   const double* __restrict__ part,
                                                   int nch,
                                                   const float* __restrict__ maxpart,
                                                   double* __restrict__ mt,
                                                   float* __restrict__ Map) {
    int b = blockIdx.y;
    int t = threadIdx.x;
    int r = blockIdx.x * 256 + t;
    __shared__ double sK[64];
    if (t < 64) {
        double s = 0.0;
        for (int ch = 0; ch < nch; ++ch)
            s += part[((size_t)(b * GCH + ch)) * 64 + t];
        sK[t] = s;
    }
    __syncthreads();
    const float* qr = &Q[((size_t)b * LQ + r) * DD];
    double a0 = 0, a1 = 0, a2 = 0, a3 = 0;
    #pragma unroll
    for (int d = 0; d < 64; d += 4) {
        a0 += (double)qr[d + 0] * sK[d + 0];
        a1 += (double)qr[d + 1] * sK[d + 1];
        a2 += (double)qr[d + 2] * sK[d + 2];
        a3 += (double)qr[d + 3] * sK[d + 3];
    }
    double m = ((a0 + a1) + (a2 + a3)) / (double)LK;
    mt[(size_t)b * LQ + r] = m;
    float mx = fmaxf(fmaxf(maxpart[((size_t)(b * MCG + 0)) * LQ + r],
                           maxpart[((size_t)(b * MCG + 1)) * LQ + r]),
                     fmaxf(maxpart[((size_t)(b * MCG + 2)) * LQ + r],
                           maxpart[((size_t)(b * MCG + 3)) * LQ + r]));
    Map[(size_t)b * LQ + r] = mx - (float)m;
}

// ---------------- K5: histogram-threshold candidate selection (1024 thr) ---
__global__ __launch_bounds__(1024) void k_select(const float* __restrict__ Map,
                                                 int* __restrict__ cand,
                                                 int* __restrict__ cand_count) {
    int b = blockIdx.x;
    int t = threadIdx.x;
    __shared__ float mv[LQ];
    __shared__ int hist[1024];
    __shared__ int seg[256];
    __shared__ float wmin[16], wmax[16];
    __shared__ float s_min, s_max;
    __shared__ int s_bstar, s_cnt;

    float lmin = INFINITY, lmax = -INFINITY;
    for (int i = t; i < LQ; i += 1024) {
        float v = Map[(size_t)b * LQ + i];
        mv[i] = v;
        lmin = fminf(lmin, v);
        lmax = fmaxf(lmax, v);
    }
    #pragma unroll
    for (int m = 1; m < 64; m <<= 1) {
        lmin = fminf(lmin, __shfl_xor(lmin, m));
        lmax = fmaxf(lmax, __shfl_xor(lmax, m));
    }
    int wid = t >> 6;
    if ((t & 63) == 0) { wmin[wid] = lmin; wmax[wid] = lmax; }
    if (t < 1024) hist[t] = 0;
    __syncthreads();
    if (t == 0) {
        float mn = wmin[0], mx = wmax[0];
        #pragma unroll
        for (int i = 1; i < 16; ++i) { mn = fminf(mn, wmin[i]); mx = fmaxf(mx, wmax[i]); }
        s_min = mn; s_max = mx;
        s_cnt = 0;
        s_bstar = 1023;
    }
    __syncthreads();
    float vmin = s_min;
    float w = (s_max - vmin) * (1.0f / 1024.0f);
    if (w <= 0.f) w = 1e-30f;
    float inv = 1.0f / w;
    for (int i = t; i < LQ; i += 1024) {
        int bin = (int)((mv[i] - vmin) * inv);
        bin = min(max(bin, 0), 1023);
        atomicAdd(&hist[bin], 1);
    }
    __syncthreads();
    int h0 = 0, h1 = 0, h2 = 0, h3 = 0;
    if (t < 256) {
        h0 = hist[t * 4 + 0]; h1 = hist[t * 4 + 1];
        h2 = hist[t * 4 + 2]; h3 = hist[t * 4 + 3];
        seg[t] = h0 + h1 + h2 + h3;
    }
    __syncthreads();
    for (int off = 1; off < 256; off <<= 1) {
        int v = 0, add = 0;
        if (t < 256) { v = seg[t]; add = (t >= off) ? seg[t - off] : 0; }
        __syncthreads();
        if (t < 256) seg[t] = v + add;
        __syncthreads();
    }
    if (t < 256) {
        int prev = (t == 0) ? 0 : seg[t - 1];
        if (seg[t] >= CUMTHR && prev < CUMTHR) {
            int cum = prev, bs = t * 4 + 3;
            if (cum + h0 >= CUMTHR) bs = t * 4;
            else if (cum + h0 + h1 >= CUMTHR) bs = t * 4 + 1;
            else if (cum + h0 + h1 + h2 >= CUMTHR) bs = t * 4 + 2;
            s_bstar = bs;
        }
    }
    __syncthreads();
    int bstar = s_bstar;
    for (int i = t; i < LQ; i += 1024) {
        int bin = (int)((mv[i] - vmin) * inv);
        bin = min(max(bin, 0), 1023);
        if (bin <= bstar) {
            int p = atomicAdd(&s_cnt, 1);
            if (p < CCAP) cand[b * CCAP + p] = i;
        }
    }
    __syncthreads();
    if (t == 0) cand_count[b] = min(s_cnt, CCAP);
}

// ---------------- K6: exact f32 max for candidates (512 thr, 8 waves) ------
__global__ __launch_bounds__(512) void k_exact(const float* __restrict__ Q,
                                               const float* __restrict__ K,
                                               const int* __restrict__ idx,
                                               const int* __restrict__ cand,
                                               const int* __restrict__ cand_count,
                                               float* __restrict__ exactpart) {
    int kc = blockIdx.x;
    int b  = blockIdx.y;
    int t = threadIdx.x;
    int lane = t & 63, w = t >> 6;     // w in 0..7
    __shared__ float Ks[128 * 64];     // 32 KB
    __shared__ float wmx[8][CCAP];     // 8 KB

    #pragma unroll
    for (int p = 0; p < 4; ++p) {
        int row = p * 32 + (t >> 4);
        int c4 = t & 15;
        int kr = idx[kc * 128 + row];
        *(float4*)&Ks[row * 64 + c4 * 4] =
            *(const float4*)&K[((size_t)b * LK + kr) * DD + c4 * 4];
    }

    int count = cand_count[b];
    int npass = (count + 127) >> 7;
    __syncthreads();

    for (int pass = 0; pass < npass; ++pass) {
        int s0 = pass * 128 + lane;
        int s1 = s0 + 64;
        float4 q0[16], q1[16];
        {
            float4 z = {0.f, 0.f, 0.f, 0.f};
            if (s0 < count) {
                const float4* qp = (const float4*)&Q[((size_t)b * LQ + cand[b * CCAP + s0]) * DD];
                #pragma unroll
                for (int i = 0; i < 16; ++i) q0[i] = qp[i];
            } else {
                #pragma unroll
                for (int i = 0; i < 16; ++i) q0[i] = z;
            }
            if (s1 < count) {
                const float4* qp = (const float4*)&Q[((size_t)b * LQ + cand[b * CCAP + s1]) * DD];
                #pragma unroll
                for (int i = 0; i < 16; ++i) q1[i] = qp[i];
            } else {
                #pragma unroll
                for (int i = 0; i < 16; ++i) q1[i] = z;
            }
        }

        float m0 = -INFINITY, m1 = -INFINITY;
        int kbeg = w * 16;
        for (int k = kbeg; k < kbeg + 16; ++k) {
            const float4* kr4 = (const float4*)&Ks[k * 64];
            float a0=0.f,a1=0.f,a2=0.f,a3=0.f;
            float c0=0.f,c1=0.f,c2=0.f,c3=0.f;
            #pragma unroll
            for (int i = 0; i < 16; i += 4) {
                float4 kv0 = kr4[i+0], kv1 = kr4[i+1], kv2 = kr4[i+2], kv3 = kr4[i+3];
                a0 = fmaf(q0[i+0].x, kv0.x, a0); a0 = fmaf(q0[i+0].y, kv0.y, a0);
                a0 = fmaf(q0[i+0].z, kv0.z, a0); a0 = fmaf(q0[i+0].w, kv0.w, a0);
                a1 = fmaf(q0[i+1].x, kv1.x, a1); a1 = fmaf(q0[i+1].y, kv1.y, a1);
                a1 = fmaf(q0[i+1].z, kv1.z, a1); a1 = fmaf(q0[i+1].w, kv1.w, a1);
                a2 = fmaf(q0[i+2].x, kv2.x, a2); a2 = fmaf(q0[i+2].y, kv2.y, a2);
                a2 = fmaf(q0[i+2].z, kv2.z, a2); a2 = fmaf(q0[i+2].w, kv2.w, a2);
                a3 = fmaf(q0[i+3].x, kv3.x, a3); a3 = fmaf(q0[i+3].y, kv3.y, a3);
                a3 = fmaf(q0[i+3].z, kv3.z, a3); a3 = fmaf(q0[i+3].w, kv3.w, a3);
                c0 = fmaf(q1[i+0].x, kv0.x, c0); c0 = fmaf(q1[i+0].y, kv0.y, c0);
                c0 = fmaf(q1[i+0].z, kv0.z, c0); c0 = fmaf(q1[i+0].w, kv0.w, c0);
                c1 = fmaf(q1[i+1].x, kv1.x, c1); c1 = fmaf(q1[i+1].y, kv1.y, c1);
                c1 = fmaf(q1[i+1].z, kv1.z, c1); c1 = fmaf(q1[i+1].w, kv1.w, c1);
                c2 = fmaf(q1[i+2].x, kv2.x, c2); c2 = fmaf(q1[i+2].y, kv2.y, c2);
                c2 = fmaf(q1[i+2].z, kv2.z, c2); c2 = fmaf(q1[i+2].w, kv2.w, c2);
                c3 = fmaf(q1[i+3].x, kv3.x, c3); c3 = fmaf(q1[i+3].y, kv3.y, c3);
                c3 = fmaf(q1[i+3].z, kv3.z, c3); c3 = fmaf(q1[i+3].w, kv3.w, c3);
            }
            m0 = fmaxf(m0, (a0 + a1) + (a2 + a3));
            m1 = fmaxf(m1, (c0 + c1) + (c2 + c3));
        }
        wmx[w][s0] = m0;
        if (s1 < CCAP) wmx[w][s1] = m1;
    }
    __syncthreads();

    if (t < count) {
        float m = -INFINITY;
        #pragma unroll
        for (int ww = 0; ww < 8; ++ww) m = fmaxf(m, wmx[ww][t]);
        exactpart[((size_t)(b * CCAP + t)) * ECH + kc] = m;
    }
}

// ---------------- K7: final top-45 (lexicographic (val, orig idx)) ---------
__global__ __launch_bounds__(64) void k_final45(const float* __restrict__ exactpart,
                                                const double* __restrict__ mt,
                                                const int* __restrict__ cand,
                                                const int* __restrict__ cand_count,
                                                int* __restrict__ Mtop) {
    int b = blockIdx.x;
    int l = threadIdx.x;
    int count = cand_count[b];
    float val[4];
    int oid[4];
    #pragma unroll
    for (int j = 0; j < 4; ++j) {
        int slot = l + j * 64;
        if (slot < count) {
            const float4* ep = (const float4*)&exactpart[((size_t)(b * CCAP + slot)) * ECH];
            float m = -INFINITY;
            #pragma unroll
            for (int k = 0; k < ECH / 4; ++k) {
                float4 v = ep[k];
                m = fmaxf(m, fmaxf(fmaxf(v.x, v.y), fmaxf(v.z, v.w)));
            }
            int r = cand[b * CCAP + slot];
            val[j] = m - (float)mt[(size_t)b * LQ + r];
            oid[j] = r;
        } else { val[j] = INFINITY; oid[j] = 0x7FFFFFFF; }
    }
    for (int it = 0; it < UU; ++it) {
        float bv = val[0]; int bi = oid[0], bj = 0;
        #pragma unroll
        for (int j = 1; j < 4; ++j)
            if (val[j] < bv || (val[j] == bv && oid[j] < bi)) { bv = val[j]; bi = oid[j]; bj = j; }
        float rv = bv; int ri = bi;
        #pragma unroll
        for (int m = 1; m < 64; m <<= 1) {
            float ov = __shfl_xor(rv, m);
            int oi = __shfl_xor(ri, m);
            if (ov < rv || (ov == rv && oi < ri)) { rv = ov; ri = oi; }
        }
        if (l == 0) Mtop[b * UU + it] = ri;
        if (rv == bv && ri == bi) val[bj] = INFINITY;
    }
}

// ---------------- K8: fused scores + chunk-softmax + PV partial (512 thr) --
__global__ __launch_bounds__(512) void k_spv(const float* __restrict__ Q,
                                             const float* __restrict__ K,
                                             const float* __restrict__ V,
                                             const int* __restrict__ Mtop,
                                             float* __restrict__ scores,
                                             float2* __restrict__ stats,
                                             float* __restrict__ partial) {
    int ch = blockIdx.x, b = blockIdx.y;
    int t = threadIdx.x;
    int lane = t & 63, w = t >> 6;   // w in 0..7
    int k0 = ch * 128;

    __shared__ float Qs[48][64];     // 12 KB
    __shared__ float Vs[128 * 64];   // 32 KB
    __shared__ float Ps[48][128];    // 24 KB (scores -> exp)
    __shared__ float2 st[48];

    for (int i = t; i < 48 * 64; i += 512) {
        int r = i >> 6, dd = i & 63;
        Qs[r][dd] = (r < UU) ? Q[((size_t)b * LQ + Mtop[b * UU + r]) * DD + dd] : 0.f;
    }
    for (int p = 0; p < 4; ++p) {
        int lin = p * 2048 + t * 4;
        *(float4*)&Vs[lin] = *(const float4*)&V[((size_t)b * LK + k0) * DD + lin];
    }
    __syncthreads();

    // ---- scores: key = t&127, row-quarter = t>>7 (12 rows each, last 9)
    {
        int key = t & 127;
        int rq = t >> 7;                 // 0..3
        int r0 = rq * 12;
        int r1 = min(r0 + 12, UU);
        const float* Krow = &K[((size_t)(b * LK + k0 + key)) * DD];
        float4 kv[16];
        #pragma unroll
        for (int i = 0; i < 16; ++i) kv[i] = ((const float4*)Krow)[i];
        for (int r = r0; r < r1; ++r) {
            const float4* qr = (const float4*)&Qs[r][0];
            float d0 = 0.f, d1 = 0.f, d2 = 0.f, d3 = 0.f;
            #pragma unroll
            for (int i = 0; i < 16; i += 4) {
                float4 q0 = qr[i+0], q1 = qr[i+1], q2 = qr[i+2], q3 = qr[i+3];
                d0 = fmaf(q0.x, kv[i+0].x, d0); d0 = fmaf(q0.y, kv[i+0].y, d0);
                d0 = fmaf(q0.z, kv[i+0].z, d0); d0 = fmaf(q0.w, kv[i+0].w, d0);
                d1 = fmaf(q1.x, kv[i+1].x, d1); d1 = fmaf(q1.y, kv[i+1].y, d1);
                d1 = fmaf(q1.z, kv[i+1].z, d1); d1 = fmaf(q1.w, kv[i+1].w, d1);
                d2 = fmaf(q2.x, kv[i+2].x, d2); d2 = fmaf(q2.y, kv[i+2].y, d2);
                d2 = fmaf(q2.z, kv[i+2].z, d2); d2 = fmaf(q2.w, kv[i+2].w, d2);
                d3 = fmaf(q3.x, kv[i+3].x, d3); d3 = fmaf(q3.y, kv[i+3].y, d3);
                d3 = fmaf(q3.z, kv[i+3].z, d3); d3 = fmaf(q3.w, kv[i+3].w, d3);
            }
            float sc = ((d0 + d1) + (d2 + d3)) * 0.125f;
            Ps[r][key] = sc;
            scores[((size_t)(b * UU + r)) * LK + k0 + key] = sc;
        }
    }
    __syncthreads();

    // ---- per-row chunk stats + exponentiate (wave w handles rows w,w+8,..)
    for (int r = w; r < 48; r += 8) {
        if (r < UU) {
            float v0 = Ps[r][lane], v1 = Ps[r][lane + 64];
            float m = fmaxf(v0, v1);
            #pragma unroll
            for (int o = 32; o; o >>= 1) m = fmaxf(m, __shfl_xor(m, o));
            float e0 = __expf(v0 - m), e1 = __expf(v1 - m);
            float s = e0 + e1;
            #pragma unroll
            for (int o = 32; o; o >>= 1) s += __shfl_xor(s, o);
            Ps[r][lane] = e0; Ps[r][lane + 64] = e1;
            if (lane == 0) st[r] = make_float2(m, s);
        } else {
            Ps[r][lane] = 0.f; Ps[r][lane + 64] = 0.f;
        }
    }
    __syncthreads();

    // ---- PV partial: d = t&63, row-group t>>6 (6 rows each)
    {
        int d = t & 63, rg = t >> 6;     // rg in 0..7
        float acc[6];
        #pragma unroll
        for (int i = 0; i < 6; ++i) acc[i] = 0.f;
        for (int k = 0; k < 128; ++k) {
            float vv = Vs[k * 64 + d];
            #pragma unroll
            for (int i = 0; i < 6; ++i)
                acc[i] += Ps[rg * 6 + i][k] * vv;
        }
        #pragma unroll
        for (int i = 0; i < 6; ++i) {
            int r = rg * 6 + i;
            if (r < UU)
                partial[(((size_t)(b * PCH + ch)) * UU + r) * 64 + d] = acc[i];
        }
    }
    if (t < UU) stats[((size_t)(b * PCH + ch)) * UU + t] = st[t];
}

// ---------------- K9: combine chunk partials (d-quarter split, 32 blocks) --
__global__ __launch_bounds__(256) void k_combine(const float* __restrict__ partial,
                                                 const float2* __restrict__ stats,
                                                 float* __restrict__ out) {
    int dq = blockIdx.x;
    int b = blockIdx.y;
    int t = threadIdx.x;
    __shared__ float wgt[UU][PCH];
    if (t < UU) {
        float mx[PCH], sm[PCH];
        #pragma unroll
        for (int c = 0; c < PCH; ++c) {
            float2 v = stats[((size_t)(b * PCH + c)) * UU + t];
            mx[c] = v.x; sm[c] = v.y;
        }
        float m = mx[0];
        #pragma unroll
        for (int c = 1; c < PCH; ++c) m = fmaxf(m, mx[c]);
        float S = 0.f;
        #pragma unroll
        for (int c = 0; c < PCH; ++c) {
            float e = __expf(mx[c] - m);
            wgt[t][c] = e;
            S += sm[c] * e;
        }
        float inv = 1.0f / S;
        #pragma unroll
        for (int c = 0; c < PCH; ++c) wgt[t][c] *= inv;
    }
    __syncthreads();
    for (int o = t; o < UU * 16; o += 256) {
        int r = o >> 4;
        int d = dq * 16 + (o & 15);
        float s = 0.f;
        #pragma unroll 8
        for (int c = 0; c < PCH; ++c)
            s += partial[(((size_t)(b * PCH + c)) * UU + r) * 64 + d] * wgt[r][c];
        out[((size_t)(b * UU + r)) * 64 + d] = s;
    }
}

extern "C" void kernel_launch(void* const* d_in, const int* in_sizes, int n_in,
                              void* d_out, int out_size, void* d_ws, size_t ws_size,
                              hipStream_t stream) {
    const float* q   = (const float*)d_in[0];
    const float* K   = (const float*)d_in[1];
    const float* V   = (const float*)d_in[2];
    const int*   idx = (const int*)d_in[3];
    int Upart = in_sizes[3];
    int nch = (Upart + 127) / 128;

    char* ws = (char*)d_ws;
    size_t off = 0;
    unsigned short* Kg = (unsigned short*)(ws + off); off += (size_t)BB * 4096 * 64 * 2; // 4 MB
    float*  maxpart   = (float*)(ws + off);  off += (size_t)BB * MCG * LQ * 4;           // 512 KB
    double* mt        = (double*)(ws + off); off += (size_t)BB * LQ * 8;
    float*  Map       = (float*)(ws + off);  off += (size_t)BB * LQ * 4;
    int*    cand      = (int*)(ws + off);    off += (size_t)BB * CCAP * 4;
    int*    cand_cnt  = (int*)(ws + off);    off += 256;
    int*    Mtop      = (int*)(ws + off);    off += 2048;
    float2* stats     = (float2*)(ws + off); off += (size_t)BB * PCH * UU * 8 + 256;
    float*  partial   = (float*)(ws + off);  off += (size_t)BB * PCH * UU * 64 * 4;
    // disjoint-liveness aliases onto the partial region:
    double* sumKpart  = (double*)partial;    // live: k_gatherK -> k_meanmerge (128 KB)
    float*  exactpart = (float*)partial;     // live: k_exact -> k_final45 (256 KB)

    float* out_attn   = (float*)d_out;
    float* out_scores = out_attn + BB * UU * 64;

    k_gatherK  <<<dim3(nch, BB), 512, 0, stream>>>(K, idx, Upart, Kg, sumKpart);
    k_mfmaM    <<<dim3(LQ / 256, MCG, BB), 256, 0, stream>>>(q, Kg, maxpart);
    k_meanmerge<<<dim3(LQ / 256, BB), 256, 0, stream>>>(q, sumKpart, nch, maxpart, mt, Map);
    k_select   <<<dim3(BB), 1024, 0, stream>>>(Map, cand, cand_cnt);
    k_exact    <<<dim3(ECH, BB), 512, 0, stream>>>(q, K, idx, cand, cand_cnt, exactpart);
    k_final45  <<<dim3(BB), 64, 0, stream>>>(exactpart, mt, cand, cand_cnt, Mtop);
    k_spv      <<<dim3(PCH, BB), 512, 0, stream>>>(q, K, V, Mtop, out_scores, stats, partial);
    k_combine  <<<dim3(4, BB), 256, 0, stream>>>(partial, stats, out_attn);
}

// Round 21
// 132.322 us; speedup vs baseline: 1.2607x; 1.2607x over previous
//
#include <hip/hip_runtime.h>
#include <hip/hip_bf16.h>
#include <math.h>

#define BB 8
#define LQ 4096
#define LK 4096
#define DD 64
#define UU 45    // top-k rows (min(5*ceil(log1p(4096)), 4096) = 45)
#define CCAP 256 // candidate capacity
#define CUMTHR 96
#define ECH 32   // exact-phase key chunks (128 keys each)
#define PCH 32   // pv/score chunks (128 keys each)
#define MCG 4    // mfmaM column groups (1024 sampled cols each)
#define GCH 32   // gather chunks (128 rows each)

typedef __bf16 bf16x8 __attribute__((ext_vector_type(8)));
typedef unsigned short ushort8 __attribute__((ext_vector_type(8)));
typedef float f32x4 __attribute__((ext_vector_type(4)));

__device__ inline unsigned short f2bf(float x) {   // RNE float->bf16 bits
    unsigned u = __builtin_bit_cast(unsigned, x);
    return (unsigned short)((u + 0x7FFF + ((u >> 16) & 1)) >> 16);
}

__device__ inline void gl_lds16(const void* g, void* l) {
    __builtin_amdgcn_global_load_lds(
        (const __attribute__((address_space(1))) unsigned int*)g,
        (__attribute__((address_space(3))) unsigned int*)l, 16, 0, 0);
}

// ---------------- K0: gather+convert sampled K rows, fused f64 partial sums
// 128 rows per chunk, 512 threads (8 waves) -> 2 gathered loads per thread.
__global__ __launch_bounds__(512) void k_gatherK(const float* __restrict__ K,
                                                 const int* __restrict__ idx,
                                                 int Upart,
                                                 unsigned short* __restrict__ Kg,
                                                 double* __restrict__ part) {
    int b = blockIdx.y;
    int chunk = blockIdx.x;
    int u0 = chunk * 128;
    int t = threadIdx.x;
    int pt = t & 7;            // d-part (8 floats each)

    double acc[8] = {0,0,0,0,0,0,0,0};
    #pragma unroll
    for (int i = 0; i < 2; ++i) {
        int lin = i * 512 + t;             // part stays == pt as i varies
        int u = u0 + (lin >> 3);
        if (u < Upart) {
            int kr = idx[u];
            const float* src = &K[((size_t)b * LK + kr) * DD + pt * 8];
            float4 v0 = *(const float4*)src;
            float4 v1 = *(const float4*)(src + 4);
            ushort8 pk;
            pk[0]=f2bf(v0.x); pk[1]=f2bf(v0.y); pk[2]=f2bf(v0.z); pk[3]=f2bf(v0.w);
            pk[4]=f2bf(v1.x); pk[5]=f2bf(v1.y); pk[6]=f2bf(v1.z); pk[7]=f2bf(v1.w);
            *(ushort8*)&Kg[((size_t)b * 4096 + u) * 64 + pt * 8] = pk;
            acc[0] += (double)v0.x; acc[1] += (double)v0.y;
            acc[2] += (double)v0.z; acc[3] += (double)v0.w;
            acc[4] += (double)v1.x; acc[5] += (double)v1.y;
            acc[6] += (double)v1.z; acc[7] += (double)v1.w;
        }
    }
    __shared__ double sred[64][64];   // 32 KB
    int rg = t >> 3;           // 0..63 row-group
    #pragma unroll
    for (int j = 0; j < 8; ++j) sred[rg][pt * 8 + j] = acc[j];
    __syncthreads();
    if (t < 64) {
        double s = 0.0;
        #pragma unroll
        for (int r = 0; r < 64; ++r) s += sred[r][t];
        part[((size_t)(b * GCH + chunk)) * 64 + t] = s;
    }
}

// ---------------- K2: approx row-max of q@Ks^T via bf16 MFMA ---------------
// Block: 256 Q-rows x 1024 sampled cols (8 tiles of 128). 4 waves; each wave
// owns 64 rows via 4 A-fragments. LDS: Qs (32KB, transient) OVERLAYS the Ks
// double-buffer (2x16KB) -> total 32KB/block for high occupancy.
__global__ __launch_bounds__(256) void k_mfmaM(const float* __restrict__ Q,
                                               const unsigned short* __restrict__ Kg,
                                               float* __restrict__ maxpart) {
    int bx = blockIdx.x, cg = blockIdx.y, b = blockIdx.z;
    int t = threadIdx.x;
    int lane = t & 63, w = t >> 6;
    int row0 = bx * 256;

    __shared__ unsigned short smem[16384];   // 32 KB: Qs then Ks[2]

    // stage Q tile (reg path, f2bf, swizzled) — once per block
    for (int i = 0; i < 8; ++i) {
        int u = i * 256 + t;
        int r = u >> 3, s = u & 7;
        int c = s ^ (r & 7);
        const float* src = &Q[((size_t)b * LQ + row0 + r) * DD + c * 8];
        float4 v0 = *(const float4*)src;
        float4 v1 = *(const float4*)(src + 4);
        ushort8 pk;
        pk[0]=f2bf(v0.x); pk[1]=f2bf(v0.y); pk[2]=f2bf(v0.z); pk[3]=f2bf(v0.w);
        pk[4]=f2bf(v1.x); pk[5]=f2bf(v1.y); pk[6]=f2bf(v1.z); pk[7]=f2bf(v1.w);
        *(ushort8*)&smem[r * 64 + s * 8] = pk;
    }
    __syncthreads();   // Q staged

    // hoist A fragments to registers; Qs LDS is dead afterwards
    bf16x8 afr[4][2];
    #pragma unroll
    for (int rf = 0; rf < 4; ++rf)
        #pragma unroll
        for (int kh = 0; kh < 2; ++kh) {
            int r = w * 64 + rf * 16 + (lane & 15);
            int slot = (kh * 4 + (lane >> 4)) ^ (r & 7);
            afr[rf][kh] = __builtin_bit_cast(bf16x8, *(const ushort8*)&smem[r * 64 + slot * 8]);
        }
    __syncthreads();   // all afr reads done -> smem reusable as Ks[2]

    int krl = lane >> 3;                      // key within 8-key segment
    int kc8 = (lane & 7) ^ (krl & 7);         // inverse-swizzled global chunk
    const unsigned short* kgb = Kg + ((size_t)b * 4096 + cg * 1024) * 64;

    #define STAGE_K(buf, tile)                                                  \
        {                                                                       \
            _Pragma("unroll")                                                   \
            for (int i_ = 0; i_ < 4; ++i_) {                                    \
                int seg_ = w * 4 + i_;                                          \
                const unsigned short* g_ =                                      \
                    kgb + ((size_t)((tile) * 128 + seg_ * 8 + krl)) * 64 + kc8 * 8; \
                gl_lds16(g_, &smem[(buf) * 8192 + seg_ * 512]);                 \
            }                                                                   \
        }

    STAGE_K(0, 0)
    __syncthreads();   // Ks[0] drained

    float rowmax[4][4];
    #pragma unroll
    for (int rf = 0; rf < 4; ++rf)
        #pragma unroll
        for (int g = 0; g < 4; ++g) rowmax[rf][g] = -INFINITY;

    for (int tile = 0; tile < 8; ++tile) {
        int cur = tile & 1;
        if (tile < 7) STAGE_K(cur ^ 1, tile + 1)   // prefetch next tile

        #pragma unroll
        for (int cf = 0; cf < 8; ++cf) {
            f32x4 acc[4];
            #pragma unroll
            for (int rf = 0; rf < 4; ++rf) acc[rf] = (f32x4){0.f, 0.f, 0.f, 0.f};
            #pragma unroll
            for (int kh = 0; kh < 2; ++kh) {
                int ccol = cf * 16 + (lane & 15);
                int slot = (kh * 4 + (lane >> 4)) ^ (ccol & 7);
                bf16x8 bfr = __builtin_bit_cast(bf16x8,
                    *(const ushort8*)&smem[cur * 8192 + ccol * 64 + slot * 8]);
                #pragma unroll
                for (int rf = 0; rf < 4; ++rf)
                    acc[rf] = __builtin_amdgcn_mfma_f32_16x16x32_bf16(afr[rf][kh], bfr, acc[rf], 0, 0, 0);
            }
            #pragma unroll
            for (int rf = 0; rf < 4; ++rf)
                #pragma unroll
                for (int g = 0; g < 4; ++g)
                    rowmax[rf][g] = fmaxf(rowmax[rf][g], acc[rf][g]);
        }
        __syncthreads();   // drain prefetch loads + protect Ks[cur] reuse
    }

    #pragma unroll
    for (int rf = 0; rf < 4; ++rf)
        #pragma unroll
        for (int g = 0; g < 4; ++g) {
            float m = rowmax[rf][g];
            m = fmaxf(m, __shfl_xor(m, 1));
            m = fmaxf(m, __shfl_xor(m, 2));
            m = fmaxf(m, __shfl_xor(m, 4));
            m = fmaxf(m, __shfl_xor(m, 8));
            if ((lane & 15) == 0) {
                int row = row0 + w * 64 + rf * 16 + (lane >> 4) * 4 + g;
                maxpart[((size_t)(b * MCG + cg)) * LQ + row] = m;
            }
        }
}

// ---------------- K3: fused sumK-reduce + mt + Map -------------------------
__global__ __launch_bounds__(256) void k_meanmerge(const float* __restrict__ Q,
                                                   const double* __restrict__ part,
                                                   int nch,
                                                   const float* __restrict__ maxpart,
                                                   double* __restrict__ mt,
                                                   float* __restrict__ Map) {
    int b = blockIdx.y;
    int t = threadIdx.x;
    int r = blockIdx.x * 256 + t;
    __shared__ double sK[64];
    if (t < 64) {
        double s = 0.0;
        for (int ch = 0; ch < nch; ++ch)
            s += part[((size_t)(b * GCH + ch)) * 64 + t];
        sK[t] = s;
    }
    __syncthreads();
    const float* qr = &Q[((size_t)b * LQ + r) * DD];
    double a0 = 0, a1 = 0, a2 = 0, a3 = 0;
    #pragma unroll
    for (int d = 0; d < 64; d += 4) {
        a0 += (double)qr[d + 0] * sK[d + 0];
        a1 += (double)qr[d + 1] * sK[d + 1];
        a2 += (double)qr[d + 2] * sK[d + 2];
        a3 += (double)qr[d + 3] * sK[d + 3];
    }
    double m = ((a0 + a1) + (a2 + a3)) / (double)LK;
    mt[(size_t)b * LQ + r] = m;
    float mx = fmaxf(fmaxf(maxpart[((size_t)(b * MCG + 0)) * LQ + r],
                           maxpart[((size_t)(b * MCG + 1)) * LQ + r]),
                     fmaxf(maxpart[((size_t)(b * MCG + 2)) * LQ + r],
                           maxpart[((size_t)(b * MCG + 3)) * LQ + r]));
    Map[(size_t)b * LQ + r] = mx - (float)m;
}

// ---------------- K5: histogram-threshold candidate selection (1024 thr) ---
__global__ __launch_bounds__(1024) void k_select(const float* __restrict__ Map,
                                                 int* __restrict__ cand,
                                                 int* __restrict__ cand_count) {
    int b = blockIdx.x;
    int t = threadIdx.x;
    __shared__ float mv[LQ];
    __shared__ int hist[1024];
    __shared__ int seg[256];
    __shared__ float wmin[16], wmax[16];
    __shared__ float s_min, s_max;
    __shared__ int s_bstar, s_cnt;

    float lmin = INFINITY, lmax = -INFINITY;
    for (int i = t; i < LQ; i += 1024) {
        float v = Map[(size_t)b * LQ + i];
        mv[i] = v;
        lmin = fminf(lmin, v);
        lmax = fmaxf(lmax, v);
    }
    #pragma unroll
    for (int m = 1; m < 64; m <<= 1) {
        lmin = fminf(lmin, __shfl_xor(lmin, m));
        lmax = fmaxf(lmax, __shfl_xor(lmax, m));
    }
    int wid = t >> 6;
    if ((t & 63) == 0) { wmin[wid] = lmin; wmax[wid] = lmax; }
    if (t < 1024) hist[t] = 0;
    __syncthreads();
    if (t == 0) {
        float mn = wmin[0], mx = wmax[0];
        #pragma unroll
        for (int i = 1; i < 16; ++i) { mn = fminf(mn, wmin[i]); mx = fmaxf(mx, wmax[i]); }
        s_min = mn; s_max = mx;
        s_cnt = 0;
        s_bstar = 1023;
    }
    __syncthreads();
    float vmin = s_min;
    float w = (s_max - vmin) * (1.0f / 1024.0f);
    if (w <= 0.f) w = 1e-30f;
    float inv = 1.0f / w;
    for (int i = t; i < LQ; i += 1024) {
        int bin = (int)((mv[i] - vmin) * inv);
        bin = min(max(bin, 0), 1023);
        atomicAdd(&hist[bin], 1);
    }
    __syncthreads();
    int h0 = 0, h1 = 0, h2 = 0, h3 = 0;
    if (t < 256) {
        h0 = hist[t * 4 + 0]; h1 = hist[t * 4 + 1];
        h2 = hist[t * 4 + 2]; h3 = hist[t * 4 + 3];
        seg[t] = h0 + h1 + h2 + h3;
    }
    __syncthreads();
    for (int off = 1; off < 256; off <<= 1) {
        int v = 0, add = 0;
        if (t < 256) { v = seg[t]; add = (t >= off) ? seg[t - off] : 0; }
        __syncthreads();
        if (t < 256) seg[t] = v + add;
        __syncthreads();
    }
    if (t < 256) {
        int prev = (t == 0) ? 0 : seg[t - 1];
        if (seg[t] >= CUMTHR && prev < CUMTHR) {
            int cum = prev, bs = t * 4 + 3;
            if (cum + h0 >= CUMTHR) bs = t * 4;
            else if (cum + h0 + h1 >= CUMTHR) bs = t * 4 + 1;
            else if (cum + h0 + h1 + h2 >= CUMTHR) bs = t * 4 + 2;
            s_bstar = bs;
        }
    }
    __syncthreads();
    int bstar = s_bstar;
    for (int i = t; i < LQ; i += 1024) {
        int bin = (int)((mv[i] - vmin) * inv);
        bin = min(max(bin, 0), 1023);
        if (bin <= bstar) {
            int p = atomicAdd(&s_cnt, 1);
            if (p < CCAP) cand[b * CCAP + p] = i;
        }
    }
    __syncthreads();
    if (t == 0) cand_count[b] = min(s_cnt, CCAP);
}

// ---------------- K6: exact f32 max for candidates (512 thr, 8 waves) ------
__global__ __launch_bounds__(512) void k_exact(const float* __restrict__ Q,
                                               const float* __restrict__ K,
                                               const int* __restrict__ idx,
                                               const int* __restrict__ cand,
                                               const int* __restrict__ cand_count,
                                               float* __restrict__ exactpart) {
    int kc = blockIdx.x;
    int b  = blockIdx.y;
    int t = threadIdx.x;
    int lane = t & 63, w = t >> 6;     // w in 0..7
    __shared__ float Ks[128 * 64];     // 32 KB
    __shared__ float wmx[8][CCAP];     // 8 KB

    #pragma unroll
    for (int p = 0; p < 4; ++p) {
        int row = p * 32 + (t >> 4);
        int c4 = t & 15;
        int kr = idx[kc * 128 + row];
        *(float4*)&Ks[row * 64 + c4 * 4] =
            *(const float4*)&K[((size_t)b * LK + kr) * DD + c4 * 4];
    }

    int count = cand_count[b];
    int npass = (count + 127) >> 7;
    __syncthreads();

    for (int pass = 0; pass < npass; ++pass) {
        int s0 = pass * 128 + lane;
        int s1 = s0 + 64;
        float4 q0[16], q1[16];
        {
            float4 z = {0.f, 0.f, 0.f, 0.f};
            if (s0 < count) {
                const float4* qp = (const float4*)&Q[((size_t)b * LQ + cand[b * CCAP + s0]) * DD];
                #pragma unroll
                for (int i = 0; i < 16; ++i) q0[i] = qp[i];
            } else {
                #pragma unroll
                for (int i = 0; i < 16; ++i) q0[i] = z;
            }
            if (s1 < count) {
                const float4* qp = (const float4*)&Q[((size_t)b * LQ + cand[b * CCAP + s1]) * DD];
                #pragma unroll
                for (int i = 0; i < 16; ++i) q1[i] = qp[i];
            } else {
                #pragma unroll
                for (int i = 0; i < 16; ++i) q1[i] = z;
            }
        }

        float m0 = -INFINITY, m1 = -INFINITY;
        int kbeg = w * 16;
        for (int k = kbeg; k < kbeg + 16; ++k) {
            const float4* kr4 = (const float4*)&Ks[k * 64];
            float a0=0.f,a1=0.f,a2=0.f,a3=0.f;
            float c0=0.f,c1=0.f,c2=0.f,c3=0.f;
            #pragma unroll
            for (int i = 0; i < 16; i += 4) {
                float4 kv0 = kr4[i+0], kv1 = kr4[i+1], kv2 = kr4[i+2], kv3 = kr4[i+3];
                a0 = fmaf(q0[i+0].x, kv0.x, a0); a0 = fmaf(q0[i+0].y, kv0.y, a0);
                a0 = fmaf(q0[i+0].z, kv0.z, a0); a0 = fmaf(q0[i+0].w, kv0.w, a0);
                a1 = fmaf(q0[i+1].x, kv1.x, a1); a1 = fmaf(q0[i+1].y, kv1.y, a1);
                a1 = fmaf(q0[i+1].z, kv1.z, a1); a1 = fmaf(q0[i+1].w, kv1.w, a1);
                a2 = fmaf(q0[i+2].x, kv2.x, a2); a2 = fmaf(q0[i+2].y, kv2.y, a2);
                a2 = fmaf(q0[i+2].z, kv2.z, a2); a2 = fmaf(q0[i+2].w, kv2.w, a2);
                a3 = fmaf(q0[i+3].x, kv3.x, a3); a3 = fmaf(q0[i+3].y, kv3.y, a3);
                a3 = fmaf(q0[i+3].z, kv3.z, a3); a3 = fmaf(q0[i+3].w, kv3.w, a3);
                c0 = fmaf(q1[i+0].x, kv0.x, c0); c0 = fmaf(q1[i+0].y, kv0.y, c0);
                c0 = fmaf(q1[i+0].z, kv0.z, c0); c0 = fmaf(q1[i+0].w, kv0.w, c0);
                c1 = fmaf(q1[i+1].x, kv1.x, c1); c1 = fmaf(q1[i+1].y, kv1.y, c1);
                c1 = fmaf(q1[i+1].z, kv1.z, c1); c1 = fmaf(q1[i+1].w, kv1.w, c1);
                c2 = fmaf(q1[i+2].x, kv2.x, c2); c2 = fmaf(q1[i+2].y, kv2.y, c2);
                c2 = fmaf(q1[i+2].z, kv2.z, c2); c2 = fmaf(q1[i+2].w, kv2.w, c2);
                c3 = fmaf(q1[i+3].x, kv3.x, c3); c3 = fmaf(q1[i+3].y, kv3.y, c3);
                c3 = fmaf(q1[i+3].z, kv3.z, c3); c3 = fmaf(q1[i+3].w, kv3.w, c3);
            }
            m0 = fmaxf(m0, (a0 + a1) + (a2 + a3));
            m1 = fmaxf(m1, (c0 + c1) + (c2 + c3));
        }
        wmx[w][s0] = m0;
        if (s1 < CCAP) wmx[w][s1] = m1;
    }
    __syncthreads();

    if (t < count) {
        float m = -INFINITY;
        #pragma unroll
        for (int ww = 0; ww < 8; ++ww) m = fmaxf(m, wmx[ww][t]);
        exactpart[((size_t)(b * CCAP + t)) * ECH + kc] = m;
    }
}

// ---------------- K7: final top-45 (lexicographic (val, orig idx)) ---------
__global__ __launch_bounds__(64) void k_final45(const float* __restrict__ exactpart,
                                                const double* __restrict__ mt,
                                                const int* __restrict__ cand,
                                                const int* __restrict__ cand_count,
                                                int* __restrict__ Mtop) {
    int b = blockIdx.x;
    int l = threadIdx.x;
    int count = cand_count[b];
    float val[4];
    int oid[4];
    #pragma unroll
    for (int j = 0; j < 4; ++j) {
        int slot = l + j * 64;
        if (slot < count) {
            const float4* ep = (const float4*)&exactpart[((size_t)(b * CCAP + slot)) * ECH];
            float m = -INFINITY;
            #pragma unroll
            for (int k = 0; k < ECH / 4; ++k) {
                float4 v = ep[k];
                m = fmaxf(m, fmaxf(fmaxf(v.x, v.y), fmaxf(v.z, v.w)));
            }
            int r = cand[b * CCAP + slot];
            val[j] = m - (float)mt[(size_t)b * LQ + r];
            oid[j] = r;
        } else { val[j] = INFINITY; oid[j] = 0x7FFFFFFF; }
    }
    for (int it = 0; it < UU; ++it) {
        float bv = val[0]; int bi = oid[0], bj = 0;
        #pragma unroll
        for (int j = 1; j < 4; ++j)
            if (val[j] < bv || (val[j] == bv && oid[j] < bi)) { bv = val[j]; bi = oid[j]; bj = j; }
        float rv = bv; int ri = bi;
        #pragma unroll
        for (int m = 1; m < 64; m <<= 1) {
            float ov = __shfl_xor(rv, m);
            int oi = __shfl_xor(ri, m);
            if (ov < rv || (ov == rv && oi < ri)) { rv = ov; ri = oi; }
        }
        if (l == 0) Mtop[b * UU + it] = ri;
        if (rv == bv && ri == bi) val[bj] = INFINITY;
    }
}

// ---------------- K8: fused scores + chunk-softmax + PV partial (512 thr) --
__global__ __launch_bounds__(512) void k_spv(const float* __restrict__ Q,
                                             const float* __restrict__ K,
                                             const float* __restrict__ V,
                                             const int* __restrict__ Mtop,
                                             float* __restrict__ scores,
                                             float2* __restrict__ stats,
                                             float* __restrict__ partial) {
    int ch = blockIdx.x, b = blockIdx.y;
    int t = threadIdx.x;
    int lane = t & 63, w = t >> 6;   // w in 0..7
    int k0 = ch * 128;

    __shared__ float Qs[48][64];     // 12 KB
    __shared__ float Vs[128 * 64];   // 32 KB
    __shared__ float Ps[48][128];    // 24 KB (scores -> exp)
    __shared__ float2 st[48];

    for (int i = t; i < 48 * 64; i += 512) {
        int r = i >> 6, dd = i & 63;
        Qs[r][dd] = (r < UU) ? Q[((size_t)b * LQ + Mtop[b * UU + r]) * DD + dd] : 0.f;
    }
    for (int p = 0; p < 4; ++p) {
        int lin = p * 2048 + t * 4;
        *(float4*)&Vs[lin] = *(const float4*)&V[((size_t)b * LK + k0) * DD + lin];
    }
    __syncthreads();

    // ---- scores: key = t&127, row-quarter = t>>7 (12 rows each, last 9)
    {
        int key = t & 127;
        int rq = t >> 7;                 // 0..3
        int r0 = rq * 12;
        int r1 = min(r0 + 12, UU);
        const float* Krow = &K[((size_t)(b * LK + k0 + key)) * DD];
        float4 kv[16];
        #pragma unroll
        for (int i = 0; i < 16; ++i) kv[i] = ((const float4*)Krow)[i];
        for (int r = r0; r < r1; ++r) {
            const float4* qr = (const float4*)&Qs[r][0];
            float d0 = 0.f, d1 = 0.f, d2 = 0.f, d3 = 0.f;
            #pragma unroll
            for (int i = 0; i < 16; i += 4) {
                float4 q0 = qr[i+0], q1 = qr[i+1], q2 = qr[i+2], q3 = qr[i+3];
                d0 = fmaf(q0.x, kv[i+0].x, d0); d0 = fmaf(q0.y, kv[i+0].y, d0);
                d0 = fmaf(q0.z, kv[i+0].z, d0); d0 = fmaf(q0.w, kv[i+0].w, d0);
                d1 = fmaf(q1.x, kv[i+1].x, d1); d1 = fmaf(q1.y, kv[i+1].y, d1);
                d1 = fmaf(q1.z, kv[i+1].z, d1); d1 = fmaf(q1.w, kv[i+1].w, d1);
                d2 = fmaf(q2.x, kv[i+2].x, d2); d2 = fmaf(q2.y, kv[i+2].y, d2);
                d2 = fmaf(q2.z, kv[i+2].z, d2); d2 = fmaf(q2.w, kv[i+2].w, d2);
                d3 = fmaf(q3.x, kv[i+3].x, d3); d3 = fmaf(q3.y, kv[i+3].y, d3);
                d3 = fmaf(q3.z, kv[i+3].z, d3); d3 = fmaf(q3.w, kv[i+3].w, d3);
            }
            float sc = ((d0 + d1) + (d2 + d3)) * 0.125f;
            Ps[r][key] = sc;
            scores[((size_t)(b * UU + r)) * LK + k0 + key] = sc;
        }
    }
    __syncthreads();

    // ---- per-row chunk stats + exponentiate (wave w handles rows w,w+8,..)
    for (int r = w; r < 48; r += 8) {
        if (r < UU) {
            float v0 = Ps[r][lane], v1 = Ps[r][lane + 64];
            float m = fmaxf(v0, v1);
            #pragma unroll
            for (int o = 32; o; o >>= 1) m = fmaxf(m, __shfl_xor(m, o));
            float e0 = __expf(v0 - m), e1 = __expf(v1 - m);
            float s = e0 + e1;
            #pragma unroll
            for (int o = 32; o; o >>= 1) s += __shfl_xor(s, o);
            Ps[r][lane] = e0; Ps[r][lane + 64] = e1;
            if (lane == 0) st[r] = make_float2(m, s);
        } else {
            Ps[r][lane] = 0.f; Ps[r][lane + 64] = 0.f;
        }
    }
    __syncthreads();

    // ---- PV partial: d = t&63, row-group t>>6 (6 rows each)
    {
        int d = t & 63, rg = t >> 6;     // rg in 0..7
        float acc[6];
        #pragma unroll
        for (int i = 0; i < 6; ++i) acc[i] = 0.f;
        for (int k = 0; k < 128; ++k) {
            float vv = Vs[k * 64 + d];
            #pragma unroll
            for (int i = 0; i < 6; ++i)
                acc[i] += Ps[rg * 6 + i][k] * vv;
        }
        #pragma unroll
        for (int i = 0; i < 6; ++i) {
            int r = rg * 6 + i;
            if (r < UU)
                partial[(((size_t)(b * PCH + ch)) * UU + r) * 64 + d] = acc[i];
        }
    }
    if (t < UU) stats[((size_t)(b * PCH + ch)) * UU + t] = st[t];
}

// ---------------- K9: combine chunk partials (d-quarter split, 32 blocks) --
__global__ __launch_bounds__(256) void k_combine(const float* __restrict__ partial,
                                                 const float2* __restrict__ stats,
                                                 float* __restrict__ out) {
    int dq = blockIdx.x;
    int b = blockIdx.y;
    int t = threadIdx.x;
    __shared__ float wgt[UU][PCH];
    if (t < UU) {
        float mx[PCH], sm[PCH];
        #pragma unroll
        for (int c = 0; c < PCH; ++c) {
            float2 v = stats[((size_t)(b * PCH + c)) * UU + t];
            mx[c] = v.x; sm[c] = v.y;
        }
        float m = mx[0];
        #pragma unroll
        for (int c = 1; c < PCH; ++c) m = fmaxf(m, mx[c]);
        float S = 0.f;
        #pragma unroll
        for (int c = 0; c < PCH; ++c) {
            float e = __expf(mx[c] - m);
            wgt[t][c] = e;
            S += sm[c] * e;
        }
        float inv = 1.0f / S;
        #pragma unroll
        for (int c = 0; c < PCH; ++c) wgt[t][c] *= inv;
    }
    __syncthreads();
    for (int o = t; o < UU * 16; o += 256) {
        int r = o >> 4;
        int d = dq * 16 + (o & 15);
        float s = 0.f;
        #pragma unroll 8
        for (int c = 0; c < PCH; ++c)
            s += partial[(((size_t)(b * PCH + c)) * UU + r) * 64 + d] * wgt[r][c];
        out[((size_t)(b * UU + r)) * 64 + d] = s;
    }
}

extern "C" void kernel_launch(void* const* d_in, const int* in_sizes, int n_in,
                              void* d_out, int out_size, void* d_ws, size_t ws_size,
                              hipStream_t stream) {
    const float* q   = (const float*)d_in[0];
    const float* K   = (const float*)d_in[1];
    const float* V   = (const float*)d_in[2];
    const int*   idx = (const int*)d_in[3];
    int Upart = in_sizes[3];
    int nch = (Upart + 127) / 128;

    char* ws = (char*)d_ws;
    size_t off = 0;
    unsigned short* Kg = (unsigned short*)(ws + off); off += (size_t)BB * 4096 * 64 * 2; // 4 MB
    float*  maxpart   = (float*)(ws + off);  off += (size_t)BB * MCG * LQ * 4;           // 512 KB
    double* mt        = (double*)(ws + off); off += (size_t)BB * LQ * 8;
    float*  Map       = (float*)(ws + off);  off += (size_t)BB * LQ * 4;
    int*    cand      = (int*)(ws + off);    off += (size_t)BB * CCAP * 4;
    int*    cand_cnt  = (int*)(ws + off);    off += 256;
    int*    Mtop      = (int*)(ws + off);    off += 2048;
    float2* stats     = (float2*)(ws + off); off += (size_t)BB * PCH * UU * 8 + 256;
    float*  partial   = (float*)(ws + off);  off += (size_t)BB * PCH * UU * 64 * 4;
    // disjoint-liveness aliases onto the partial region:
    double* sumKpart  = (double*)partial;    // live: k_gatherK -> k_meanmerge (128 KB)
    float*  exactpart = (float*)partial;     // live: k_exact -> k_final45 (256 KB)

    float* out_attn   = (float*)d_out;
    float* out_scores = out_attn + BB * UU * 64;

    k_gatherK  <<<dim3(nch, BB), 512, 0, stream>>>(K, idx, Upart, Kg, sumKpart);
    k_mfmaM    <<<dim3(LQ / 256, MCG, BB), 256, 0, stream>>>(q, Kg, maxpart);
    k_meanmerge<<<dim3(LQ / 256, BB), 256, 0, stream>>>(q, sumKpart, nch, maxpart, mt, Map);
    k_select   <<<dim3(BB), 1024, 0, stream>>>(Map, cand, cand_cnt);
    k_exact    <<<dim3(ECH, BB), 512, 0, stream>>>(q, K, idx, cand, cand_cnt, exactpart);
    k_final45  <<<dim3(BB), 64, 0, stream>>>(exactpart, mt, cand, cand_cnt, Mtop);
    k_spv      <<<dim3(PCH, BB), 512, 0, stream>>>(q, K, V, Mtop, out_scores, stats, partial);
    k_combine  <<<dim3(4, BB), 256, 0, stream>>>(partial, stats, out_attn);
}